// Round 14
// baseline (266.637 us; speedup 1.0000x reference)
//
#include <hip/hip_runtime.h>
#include <hip/hip_bf16.h>
#include <math.h>

#define Bb 8
#define Tt 512
#define Cc 512
#define Hh 8
#define HKV 4
#define Dd 64

typedef __attribute__((ext_vector_type(8))) short short8;
typedef __attribute__((ext_vector_type(4))) float float4v;
typedef __attribute__((ext_vector_type(2))) __fp16 h2;   // matches cvt_pkrtz return
typedef __attribute__((ext_vector_type(8))) __fp16 half8; // f16 MFMA fragment

__device__ __forceinline__ h2 u2h(unsigned u) {
  union { unsigned u; h2 h; } x; x.u = u; return x.h;
}
__device__ __forceinline__ unsigned h2u(h2 h) {
  union { h2 h; unsigned u; } x; x.h = h; return x.u;
}
__device__ __forceinline__ float fdot2(h2 a, h2 b, float c) {
#if __has_builtin(__builtin_amdgcn_fdot2)
  return __builtin_amdgcn_fdot2(a, b, c, false);
#else
  return fmaf((float)a.x, (float)b.x, fmaf((float)a.y, (float)b.y, c));
#endif
}

__device__ __forceinline__ float wave_reduce_sum(float v) {
#pragma unroll
  for (int off = 32; off > 0; off >>= 1) v += __shfl_xor(v, off, 64);
  return v;
}
__device__ __forceinline__ unsigned pack_bf2(float a, float b) {
  __hip_bfloat162 h = __float22bfloat162_rn(make_float2(a, b));
  return *(unsigned*)&h;
}

// ---------------- fused prep: conv_w | build_pw (conv_x now fused into qkv) ----------------
__global__ __launch_bounds__(256) void prep(
    const float* __restrict__ Wq, const float* __restrict__ Wk,
    const float* __restrict__ Wv, const float* __restrict__ Wp,
    const float* __restrict__ P, const float* __restrict__ sigma,
    unsigned short* __restrict__ Wtq, unsigned short* __restrict__ Wtp,
    unsigned short* __restrict__ Pwh) {
  const int bid = blockIdx.x;
  const int t = threadIdx.x;
  if (bid < 192) {
    __shared__ float Ts[64][65];
    const int k0 = (bid & 7) << 6;
    const int n0 = (bid >> 3) << 6;
    const float* src; int ld, nc0; unsigned short* dst; int ndst;
    if (n0 < 512)       { src = Wq; ld = 512; nc0 = n0;        dst = Wtq; ndst = n0; }
    else if (n0 < 768)  { src = Wk; ld = 256; nc0 = n0 - 512;  dst = Wtq; ndst = n0; }
    else if (n0 < 1024) { src = Wv; ld = 256; nc0 = n0 - 768;  dst = Wtq; ndst = n0; }
    else                { src = Wp; ld = 512; nc0 = n0 - 1024; dst = Wtp; ndst = n0 - 1024; }
    const int r = t >> 4, c4 = (t & 15) << 2;
#pragma unroll
    for (int rr = 0; rr < 4; ++rr) {
      int row = (rr << 4) + r;
      float4 f = *(const float4*)&src[(k0 + row) * ld + nc0 + c4];
      Ts[row][c4] = f.x; Ts[row][c4 + 1] = f.y;
      Ts[row][c4 + 2] = f.z; Ts[row][c4 + 3] = f.w;
    }
    __syncthreads();
#pragma unroll
    for (int rr = 0; rr < 4; ++rr) {
      int nr = (rr << 4) + r;
      unsigned u0 = pack_bf2(Ts[c4][nr], Ts[c4 + 1][nr]);
      unsigned u1 = pack_bf2(Ts[c4 + 2][nr], Ts[c4 + 3][nr]);
      *(uint2*)&dst[(ndst + nr) * 512 + k0 + c4] = make_uint2(u0, u1);
    }
  } else {
    int idx = (bid - 192) * 256 + t;
    if (idx >= Hh * 1023 * 64) return;
    int d = idx & 63;
    int rem = idx >> 6;
    int dd = rem % 1023;
    int h = rem / 1023;
    float s = fabsf(sigma[h]) + 1e-6f;
    float delta = (float)(dd - 511);
    float dt = 128.0f * tanhf(delta / s) + 128.0f;
    float lo = floorf(dt);
    int ilo = (int)lo;
    float frac = dt - lo;
    ilo = max(0, min(ilo, 256));
    int ihi = min(ilo + 1, 256);
    const float* Pb = P + h * 257 * 64;
    float val = (1.0f - frac) * Pb[ilo * 64 + d] + frac * Pb[ihi * 64 + d];
    __fp16 hv = (__fp16)val;
    Pwh[idx] = *(unsigned short*)&hv;
  }
}

// ---------------- QKV MFMA GEMM: stages x fp32->bf16 in-register (conv_x fused) ----------------
__global__ __launch_bounds__(256) void qkv_mfma(
    const float* __restrict__ x, const unsigned short* __restrict__ Wt,
    unsigned short* __restrict__ qh, unsigned short* __restrict__ kh,
    unsigned short* __restrict__ vT) {
  __shared__ unsigned short As[64][72];
  __shared__ unsigned short Bs[64][72];
  const int m0 = blockIdx.x * 64;
  const int n0 = blockIdx.y * 64;
  const int t = threadIdx.x;
  const int w = t >> 6, lane = t & 63;
  const int srow = t >> 2, sc = (t & 3) << 4;
  float4v acc[4] = {{0,0,0,0},{0,0,0,0},{0,0,0,0},{0,0,0,0}};
  for (int k0 = 0; k0 < 512; k0 += 64) {
    const float* xp = &x[(m0 + srow) * 512 + k0 + sc];
    float4 f0 = *(const float4*)&xp[0];
    float4 f1 = *(const float4*)&xp[4];
    float4 f2 = *(const float4*)&xp[8];
    float4 f3 = *(const float4*)&xp[12];
    unsigned au[8] = {pack_bf2(f0.x, f0.y), pack_bf2(f0.z, f0.w),
                      pack_bf2(f1.x, f1.y), pack_bf2(f1.z, f1.w),
                      pack_bf2(f2.x, f2.y), pack_bf2(f2.z, f2.w),
                      pack_bf2(f3.x, f3.y), pack_bf2(f3.z, f3.w)};
    uint4 b0 = *(const uint4*)&Wt[(n0 + srow) * 512 + k0 + sc];
    uint4 b1 = *(const uint4*)&Wt[(n0 + srow) * 512 + k0 + sc + 8];
    __syncthreads();
    *(uint4*)&As[srow][sc] = *(uint4*)&au[0];
    *(uint4*)&As[srow][sc + 8] = *(uint4*)&au[4];
    *(uint4*)&Bs[srow][sc] = b0; *(uint4*)&Bs[srow][sc + 8] = b1;
    __syncthreads();
    const int ml = (w << 4) + (lane & 15);
    const int kq = (lane >> 4) << 3;
    short8 aF0 = *(short8*)&As[ml][kq];
    short8 aF1 = *(short8*)&As[ml][kq + 32];
#pragma unroll
    for (int nt = 0; nt < 4; ++nt) {
      const int nl = (nt << 4) + (lane & 15);
      short8 bF0 = *(short8*)&Bs[nl][kq];
      short8 bF1 = *(short8*)&Bs[nl][kq + 32];
      acc[nt] = __builtin_amdgcn_mfma_f32_16x16x32_bf16(aF0, bF0, acc[nt], 0, 0, 0);
      acc[nt] = __builtin_amdgcn_mfma_f32_16x16x32_bf16(aF1, bF1, acc[nt], 0, 0, 0);
    }
  }
  const int lane15 = lane & 15;
  const int rowbase = m0 + (w << 4) + ((lane >> 4) << 2);
  if (n0 < 768) {
    // q or k head: fused RMS-norm over the 64-wide head (= this n-tile)
#pragma unroll
    for (int r = 0; r < 4; ++r) {
      float ss = 0.0f;
#pragma unroll
      for (int nt = 0; nt < 4; ++nt) ss = fmaf(acc[nt][r], acc[nt][r], ss);
#pragma unroll
      for (int off = 1; off < 16; off <<= 1) ss += __shfl_xor(ss, off, 64);
      float sc2 = 8.0f * rsqrtf(ss + 1e-6f);
      const int row = rowbase + r;
      if (n0 < 512) {
        const int h = n0 >> 6;
#pragma unroll
        for (int nt = 0; nt < 4; ++nt) {
          __fp16 hv = (__fp16)(acc[nt][r] * sc2);
          qh[(row * Hh + h) * Dd + (nt << 4) + lane15] = *(unsigned short*)&hv;
        }
      } else {
        const int hkv = (n0 - 512) >> 6;
#pragma unroll
        for (int nt = 0; nt < 4; ++nt) {
          __fp16 hv = (__fp16)(acc[nt][r] * sc2);
          kh[(row * HKV + hkv) * Dd + (nt << 4) + lane15] = *(unsigned short*)&hv;
        }
      }
    }
  } else {
    // v transposed: vT[((b*HKV+hkv)*64 + d)*512 + t]
    const int hkv = (n0 - 768) >> 6;
    const int bb = rowbase >> 9;
    const int trow = rowbase & 511;
#pragma unroll
    for (int nt = 0; nt < 4; ++nt) {
      const int d = (nt << 4) + lane15;
      unsigned u0 = h2u(__builtin_amdgcn_cvt_pkrtz(acc[nt][0], acc[nt][1]));
      unsigned u1 = h2u(__builtin_amdgcn_cvt_pkrtz(acc[nt][2], acc[nt][3]));
      *(uint2*)&vT[((bb * HKV + hkv) * 64 + d) * 512 + trow] = make_uint2(u0, u1);
    }
  }
}

// ---------------- Proj MFMA GEMM: 64x64 tile, padded LDS ----------------
__global__ __launch_bounds__(256) void proj_mfma(
    const unsigned short* __restrict__ yb, const unsigned short* __restrict__ Wt,
    float* __restrict__ out) {
  __shared__ unsigned short As[64][72];
  __shared__ unsigned short Bs[64][72];
  const int m0 = blockIdx.x * 64;
  const int n0 = blockIdx.y * 64;
  const int t = threadIdx.x;
  const int w = t >> 6, lane = t & 63;
  const int srow = t >> 2, sc = (t & 3) << 4;
  float4v acc[4] = {{0,0,0,0},{0,0,0,0},{0,0,0,0},{0,0,0,0}};
  for (int k0 = 0; k0 < 512; k0 += 64) {
    uint4 a0 = *(const uint4*)&yb[(m0 + srow) * 512 + k0 + sc];
    uint4 a1 = *(const uint4*)&yb[(m0 + srow) * 512 + k0 + sc + 8];
    uint4 b0 = *(const uint4*)&Wt[(n0 + srow) * 512 + k0 + sc];
    uint4 b1 = *(const uint4*)&Wt[(n0 + srow) * 512 + k0 + sc + 8];
    __syncthreads();
    *(uint4*)&As[srow][sc] = a0; *(uint4*)&As[srow][sc + 8] = a1;
    *(uint4*)&Bs[srow][sc] = b0; *(uint4*)&Bs[srow][sc + 8] = b1;
    __syncthreads();
    const int ml = (w << 4) + (lane & 15);
    const int kq = (lane >> 4) << 3;
    short8 aF0 = *(short8*)&As[ml][kq];
    short8 aF1 = *(short8*)&As[ml][kq + 32];
#pragma unroll
    for (int nt = 0; nt < 4; ++nt) {
      const int nl = (nt << 4) + (lane & 15);
      short8 bF0 = *(short8*)&Bs[nl][kq];
      short8 bF1 = *(short8*)&Bs[nl][kq + 32];
      acc[nt] = __builtin_amdgcn_mfma_f32_16x16x32_bf16(aF0, bF0, acc[nt], 0, 0, 0);
      acc[nt] = __builtin_amdgcn_mfma_f32_16x16x32_bf16(aF1, bF1, acc[nt], 0, 0, 0);
    }
  }
#pragma unroll
  for (int nt = 0; nt < 4; ++nt) {
    int col = n0 + (nt << 4) + (lane & 15);
#pragma unroll
    for (int r = 0; r < 4; ++r) {
      int row = m0 + (w << 4) + ((lane >> 4) << 2) + r;
      out[row * 512 + col] = acc[nt][r];
    }
  }
}

// ---------------- Attention v10: Pw via VMEM gather; LDS = pS only ----------------
// Score: per row, Pw row gathered per-lane from global (L2-hot 128KB/head table,
// same pattern as the K gather) -> no PwS tile, no staging, one fewer barrier.
// LDS: pS[32][72] fp16 + lS = 4.7 KB. PV: MFMA f16 (A from pS, B from vT global).
__global__ __launch_bounds__(256) void attn(
    const unsigned short* __restrict__ qh, const unsigned short* __restrict__ kh,
    const unsigned short* __restrict__ vT, const unsigned short* __restrict__ Pwh,
    unsigned short* __restrict__ yb) {
  __shared__ __fp16 pS[32][72];
  __shared__ float lS[32];

  const int t = threadIdx.x;
  const int lane = t & 63;
  const int wu = __builtin_amdgcn_readfirstlane(t >> 6);
  const int bh = blockIdx.x;
  const int b = bh >> 3;
  const int h = bh & 7;
  const int hkv = h >> 1;
  const int i0 = 480 - blockIdx.y * 32;  // heavy blocks first

  float l_lane[8];
#pragma unroll
  for (int r = 0; r < 8; ++r) l_lane[r] = 0.0f;
  float4v oacc[2] = {{0, 0, 0, 0}, {0, 0, 0, 0}};

  const int prow = (wu << 3) + 63 - lane;
  const int i_base = i0 + (wu << 3);
  const unsigned short* qbase = &qh[((b * Tt + i_base) * Hh + h) * Dd];

  // PV fragment roles
  const int i16 = (wu & 1) << 4;
  const int dt0 = (wu >> 1) << 1;
  const int lm = lane & 15;
  const int kq = (lane >> 4) << 3;
  const unsigned short* vTbase = &vT[((b * HKV + hkv) * 64) * 512];

  for (int jt0 = 0; jt0 <= i0 + 31; jt0 += 64) {
    // K row for this lane -> regs (global, L2-hot)
    uint4 kr[8];
    {
      const uint4* kp = (const uint4*)&kh[((b * Tt + jt0 + lane) * HKV + hkv) * Dd];
#pragma unroll
      for (int c = 0; c < 8; ++c) kr[c] = kp[c];
    }
    const int pb0 = h * 1023 + (i0 - jt0) + 448;  // Pw table row for prow==0
    const uint4* pwrow0 = (const uint4*)&Pwh[(pb0 + prow) * 64];

    __syncthreads();   // pS rewrite vs prior PV reads

    // ---- score phase: lane = j; Pw per-lane VMEM gather, q uniform, K regs ----
    const int j = jt0 + lane;
#pragma unroll
    for (int r = 0; r < 8; ++r) {
      const uint4* qp = (const uint4*)&qbase[r * (Hh * Dd)];   // wave-uniform
      const uint4* pwp = pwrow0 + r * 8;                        // row prow + r
      float sr = 0.0f;
#pragma unroll
      for (int ch = 0; ch < 8; ++ch) {
        uint4 qu = qp[ch];
        uint4 pu = pwp[ch];
        sr = fdot2(u2h(qu.x) * u2h(pu.x), u2h(kr[ch].x), sr);
        sr = fdot2(u2h(qu.y) * u2h(pu.y), u2h(kr[ch].y), sr);
        sr = fdot2(u2h(qu.z) * u2h(pu.z), u2h(kr[ch].z), sr);
        sr = fdot2(u2h(qu.w) * u2h(pu.w), u2h(kr[ch].w), sr);
      }
      float sv = (j <= i_base + r) ? sr * 0.125f : -1e30f;
      float p = __expf(sv - 6.0f);   // fixed shift: exact softmax, no reduce
      l_lane[r] += p;
      pS[(wu << 3) + r][lane] = (__fp16)p;
    }
    __syncthreads();   // pS ready for all waves

    // ---- PV phase: MFMA f16, A from pS, B from vT (global, L1/L2-hot) ----
    half8 a0 = *(half8*)&pS[i16 + lm][kq];
    half8 a1 = *(half8*)&pS[i16 + lm][kq + 32];
#pragma unroll
    for (int dd = 0; dd < 2; ++dd) {
      const unsigned short* vp = vTbase + (((dt0 + dd) << 4) + lm) * 512 + jt0 + kq;
      half8 b0 = *(const half8*)&vp[0];
      half8 b1 = *(const half8*)&vp[32];
      oacc[dd] = __builtin_amdgcn_mfma_f32_16x16x32_f16(a0, b0, oacc[dd], 0, 0, 0);
      oacc[dd] = __builtin_amdgcn_mfma_f32_16x16x32_f16(a1, b1, oacc[dd], 0, 0, 0);
    }
  }

  // final l reduction (once), shared via lS
#pragma unroll
  for (int r = 0; r < 8; ++r) {
    float lr = wave_reduce_sum(l_lane[r]);
    if (lane == r) lS[(wu << 3) + r] = lr;
  }
  __syncthreads();

  // epilogue: C layout — row = i16 + quad*4 + reg, col = d-tile*16 + lm
#pragma unroll
  for (int dd = 0; dd < 2; ++dd) {
    const int d = ((dt0 + dd) << 4) + lm;
#pragma unroll
    for (int r = 0; r < 4; ++r) {
      const int irow = i16 + ((lane >> 4) << 2) + r;
      const float val = oacc[dd][r] / lS[irow];
      __hip_bfloat16 hv = __float2bfloat16(val);
      yb[((b * Tt + i0 + irow) * Hh + h) * Dd + d] = *(unsigned short*)&hv;
    }
  }
}

extern "C" void kernel_launch(void* const* d_in, const int* in_sizes, int n_in,
                              void* d_out, int out_size, void* d_ws, size_t ws_size,
                              hipStream_t stream) {
  const float* x     = (const float*)d_in[0];
  const float* Wq    = (const float*)d_in[1];
  const float* Wk    = (const float*)d_in[2];
  const float* Wv    = (const float*)d_in[3];
  const float* Wproj = (const float*)d_in[4];
  const float* P     = (const float*)d_in[5];
  const float* sigma = (const float*)d_in[6];
  float* out = (float*)d_out;

  float* ws = (float*)d_ws;
  unsigned short* qh  = (unsigned short*)ws;                // 2,097,152 h = 1,048,576 f
  unsigned short* kh  = (unsigned short*)(ws + 1048576);    // 1,048,576 h = 524,288 f
  unsigned short* vT  = (unsigned short*)(ws + 1572864);    // 1,048,576 h = 524,288 f
  unsigned short* Pwh = (unsigned short*)(ws + 2097152);    // 523,776 h -> 262,144 f
  unsigned short* yb  = (unsigned short*)(ws + 2359296);    // 2,097,152 h = 1,048,576 f
  unsigned short* Wtq = (unsigned short*)(ws + 3407872);    // 524,288 h = 262,144 f
  unsigned short* Wtp = (unsigned short*)(ws + 3670016);    // 262,144 h = 131,072 f

  prep<<<dim3(2238), 256, 0, stream>>>(Wq, Wk, Wv, Wproj, P, sigma, Wtq, Wtp, Pwh);
  qkv_mfma<<<dim3(64, 16), 256, 0, stream>>>(x, Wtq, qh, kh, vT);
  attn<<<dim3(64, 16), 256, 0, stream>>>(qh, kh, vT, Pwh, yb);
  proj_mfma<<<dim3(64, 8), 256, 0, stream>>>(yb, Wtp, out);
}

// Round 15
// 138.613 us; speedup vs baseline: 1.9236x; 1.9236x over previous
//
#include <hip/hip_runtime.h>
#include <hip/hip_bf16.h>
#include <math.h>

#define Bb 8
#define Tt 512
#define Cc 512
#define Hh 8
#define HKV 4
#define Dd 64

typedef __attribute__((ext_vector_type(8))) short short8;
typedef __attribute__((ext_vector_type(4))) float float4v;
typedef __attribute__((ext_vector_type(2))) __fp16 h2;   // matches cvt_pkrtz return
typedef __attribute__((ext_vector_type(8))) __fp16 half8; // f16 MFMA fragment

__device__ __forceinline__ h2 u2h(unsigned u) {
  union { unsigned u; h2 h; } x; x.u = u; return x.h;
}
__device__ __forceinline__ unsigned h2u(h2 h) {
  union { h2 h; unsigned u; } x; x.h = h; return x.u;
}
__device__ __forceinline__ float fdot2(h2 a, h2 b, float c) {
#if __has_builtin(__builtin_amdgcn_fdot2)
  return __builtin_amdgcn_fdot2(a, b, c, false);
#else
  return fmaf((float)a.x, (float)b.x, fmaf((float)a.y, (float)b.y, c));
#endif
}

__device__ __forceinline__ float wave_reduce_sum(float v) {
#pragma unroll
  for (int off = 32; off > 0; off >>= 1) v += __shfl_xor(v, off, 64);
  return v;
}
__device__ __forceinline__ unsigned pack_bf2(float a, float b) {
  __hip_bfloat162 h = __float22bfloat162_rn(make_float2(a, b));
  return *(unsigned*)&h;
}

// ---------------- fused prep: conv_w | build_pw (conv_x fused into qkv) ----------------
__global__ __launch_bounds__(256) void prep(
    const float* __restrict__ Wq, const float* __restrict__ Wk,
    const float* __restrict__ Wv, const float* __restrict__ Wp,
    const float* __restrict__ P, const float* __restrict__ sigma,
    unsigned short* __restrict__ Wtq, unsigned short* __restrict__ Wtp,
    unsigned short* __restrict__ Pwh) {
  const int bid = blockIdx.x;
  const int t = threadIdx.x;
  if (bid < 192) {
    __shared__ float Ts[64][65];
    const int k0 = (bid & 7) << 6;
    const int n0 = (bid >> 3) << 6;
    const float* src; int ld, nc0; unsigned short* dst; int ndst;
    if (n0 < 512)       { src = Wq; ld = 512; nc0 = n0;        dst = Wtq; ndst = n0; }
    else if (n0 < 768)  { src = Wk; ld = 256; nc0 = n0 - 512;  dst = Wtq; ndst = n0; }
    else if (n0 < 1024) { src = Wv; ld = 256; nc0 = n0 - 768;  dst = Wtq; ndst = n0; }
    else                { src = Wp; ld = 512; nc0 = n0 - 1024; dst = Wtp; ndst = n0 - 1024; }
    const int r = t >> 4, c4 = (t & 15) << 2;
#pragma unroll
    for (int rr = 0; rr < 4; ++rr) {
      int row = (rr << 4) + r;
      float4 f = *(const float4*)&src[(k0 + row) * ld + nc0 + c4];
      Ts[row][c4] = f.x; Ts[row][c4 + 1] = f.y;
      Ts[row][c4 + 2] = f.z; Ts[row][c4 + 3] = f.w;
    }
    __syncthreads();
#pragma unroll
    for (int rr = 0; rr < 4; ++rr) {
      int nr = (rr << 4) + r;
      unsigned u0 = pack_bf2(Ts[c4][nr], Ts[c4 + 1][nr]);
      unsigned u1 = pack_bf2(Ts[c4 + 2][nr], Ts[c4 + 3][nr]);
      *(uint2*)&dst[(ndst + nr) * 512 + k0 + c4] = make_uint2(u0, u1);
    }
  } else {
    int idx = (bid - 192) * 256 + t;
    if (idx >= Hh * 1023 * 64) return;
    int d = idx & 63;
    int rem = idx >> 6;
    int dd = rem % 1023;
    int h = rem / 1023;
    float s = fabsf(sigma[h]) + 1e-6f;
    float delta = (float)(dd - 511);
    float dt = 128.0f * tanhf(delta / s) + 128.0f;
    float lo = floorf(dt);
    int ilo = (int)lo;
    float frac = dt - lo;
    ilo = max(0, min(ilo, 256));
    int ihi = min(ilo + 1, 256);
    const float* Pb = P + h * 257 * 64;
    float val = (1.0f - frac) * Pb[ilo * 64 + d] + frac * Pb[ihi * 64 + d];
    __fp16 hv = (__fp16)val;
    Pwh[idx] = *(unsigned short*)&hv;
  }
}

// ---------------- QKV MFMA GEMM: stages x fp32->bf16 in-register (conv_x fused) ----------------
__global__ __launch_bounds__(256) void qkv_mfma(
    const float* __restrict__ x, const unsigned short* __restrict__ Wt,
    unsigned short* __restrict__ qh, unsigned short* __restrict__ kh,
    unsigned short* __restrict__ vT) {
  __shared__ unsigned short As[64][72];
  __shared__ unsigned short Bs[64][72];
  const int m0 = blockIdx.x * 64;
  const int n0 = blockIdx.y * 64;
  const int t = threadIdx.x;
  const int w = t >> 6, lane = t & 63;
  const int srow = t >> 2, sc = (t & 3) << 4;
  float4v acc[4] = {{0,0,0,0},{0,0,0,0},{0,0,0,0},{0,0,0,0}};
  for (int k0 = 0; k0 < 512; k0 += 64) {
    const float* xp = &x[(m0 + srow) * 512 + k0 + sc];
    float4 f0 = *(const float4*)&xp[0];
    float4 f1 = *(const float4*)&xp[4];
    float4 f2 = *(const float4*)&xp[8];
    float4 f3 = *(const float4*)&xp[12];
    unsigned au[8] = {pack_bf2(f0.x, f0.y), pack_bf2(f0.z, f0.w),
                      pack_bf2(f1.x, f1.y), pack_bf2(f1.z, f1.w),
                      pack_bf2(f2.x, f2.y), pack_bf2(f2.z, f2.w),
                      pack_bf2(f3.x, f3.y), pack_bf2(f3.z, f3.w)};
    uint4 b0 = *(const uint4*)&Wt[(n0 + srow) * 512 + k0 + sc];
    uint4 b1 = *(const uint4*)&Wt[(n0 + srow) * 512 + k0 + sc + 8];
    __syncthreads();
    *(uint4*)&As[srow][sc] = *(uint4*)&au[0];
    *(uint4*)&As[srow][sc + 8] = *(uint4*)&au[4];
    *(uint4*)&Bs[srow][sc] = b0; *(uint4*)&Bs[srow][sc + 8] = b1;
    __syncthreads();
    const int ml = (w << 4) + (lane & 15);
    const int kq = (lane >> 4) << 3;
    short8 aF0 = *(short8*)&As[ml][kq];
    short8 aF1 = *(short8*)&As[ml][kq + 32];
#pragma unroll
    for (int nt = 0; nt < 4; ++nt) {
      const int nl = (nt << 4) + (lane & 15);
      short8 bF0 = *(short8*)&Bs[nl][kq];
      short8 bF1 = *(short8*)&Bs[nl][kq + 32];
      acc[nt] = __builtin_amdgcn_mfma_f32_16x16x32_bf16(aF0, bF0, acc[nt], 0, 0, 0);
      acc[nt] = __builtin_amdgcn_mfma_f32_16x16x32_bf16(aF1, bF1, acc[nt], 0, 0, 0);
    }
  }
  const int lane15 = lane & 15;
  const int rowbase = m0 + (w << 4) + ((lane >> 4) << 2);
  if (n0 < 768) {
    // q or k head: fused RMS-norm over the 64-wide head (= this n-tile)
#pragma unroll
    for (int r = 0; r < 4; ++r) {
      float ss = 0.0f;
#pragma unroll
      for (int nt = 0; nt < 4; ++nt) ss = fmaf(acc[nt][r], acc[nt][r], ss);
#pragma unroll
      for (int off = 1; off < 16; off <<= 1) ss += __shfl_xor(ss, off, 64);
      float sc2 = 8.0f * rsqrtf(ss + 1e-6f);
      const int row = rowbase + r;
      if (n0 < 512) {
        const int h = n0 >> 6;
#pragma unroll
        for (int nt = 0; nt < 4; ++nt) {
          __fp16 hv = (__fp16)(acc[nt][r] * sc2);
          qh[(row * Hh + h) * Dd + (nt << 4) + lane15] = *(unsigned short*)&hv;
        }
      } else {
        const int hkv = (n0 - 512) >> 6;
#pragma unroll
        for (int nt = 0; nt < 4; ++nt) {
          __fp16 hv = (__fp16)(acc[nt][r] * sc2);
          kh[(row * HKV + hkv) * Dd + (nt << 4) + lane15] = *(unsigned short*)&hv;
        }
      }
    }
  } else {
    // v transposed: vT[((b*HKV+hkv)*64 + d)*512 + t]
    const int hkv = (n0 - 768) >> 6;
    const int bb = rowbase >> 9;
    const int trow = rowbase & 511;
#pragma unroll
    for (int nt = 0; nt < 4; ++nt) {
      const int d = (nt << 4) + lane15;
      unsigned u0 = h2u(__builtin_amdgcn_cvt_pkrtz(acc[nt][0], acc[nt][1]));
      unsigned u1 = h2u(__builtin_amdgcn_cvt_pkrtz(acc[nt][2], acc[nt][3]));
      *(uint2*)&vT[((bb * HKV + hkv) * 64 + d) * 512 + trow] = make_uint2(u0, u1);
    }
  }
}

// ---------------- Proj MFMA GEMM: 64x64 tile, padded LDS ----------------
__global__ __launch_bounds__(256) void proj_mfma(
    const unsigned short* __restrict__ yb, const unsigned short* __restrict__ Wt,
    float* __restrict__ out) {
  __shared__ unsigned short As[64][72];
  __shared__ unsigned short Bs[64][72];
  const int m0 = blockIdx.x * 64;
  const int n0 = blockIdx.y * 64;
  const int t = threadIdx.x;
  const int w = t >> 6, lane = t & 63;
  const int srow = t >> 2, sc = (t & 3) << 4;
  float4v acc[4] = {{0,0,0,0},{0,0,0,0},{0,0,0,0},{0,0,0,0}};
  for (int k0 = 0; k0 < 512; k0 += 64) {
    uint4 a0 = *(const uint4*)&yb[(m0 + srow) * 512 + k0 + sc];
    uint4 a1 = *(const uint4*)&yb[(m0 + srow) * 512 + k0 + sc + 8];
    uint4 b0 = *(const uint4*)&Wt[(n0 + srow) * 512 + k0 + sc];
    uint4 b1 = *(const uint4*)&Wt[(n0 + srow) * 512 + k0 + sc + 8];
    __syncthreads();
    *(uint4*)&As[srow][sc] = a0; *(uint4*)&As[srow][sc + 8] = a1;
    *(uint4*)&Bs[srow][sc] = b0; *(uint4*)&Bs[srow][sc + 8] = b1;
    __syncthreads();
    const int ml = (w << 4) + (lane & 15);
    const int kq = (lane >> 4) << 3;
    short8 aF0 = *(short8*)&As[ml][kq];
    short8 aF1 = *(short8*)&As[ml][kq + 32];
#pragma unroll
    for (int nt = 0; nt < 4; ++nt) {
      const int nl = (nt << 4) + (lane & 15);
      short8 bF0 = *(short8*)&Bs[nl][kq];
      short8 bF1 = *(short8*)&Bs[nl][kq + 32];
      acc[nt] = __builtin_amdgcn_mfma_f32_16x16x32_bf16(aF0, bF0, acc[nt], 0, 0, 0);
      acc[nt] = __builtin_amdgcn_mfma_f32_16x16x32_bf16(aF1, bF1, acc[nt], 0, 0, 0);
    }
  }
#pragma unroll
  for (int nt = 0; nt < 4; ++nt) {
    int col = n0 + (nt << 4) + (lane & 15);
#pragma unroll
    for (int r = 0; r < 4; ++r) {
      int row = m0 + (w << 4) + ((lane >> 4) << 2) + r;
      out[row * 512 + col] = acc[nt][r];
    }
  }
}

// ---------------- Attention v9 (restored): LDS PwS + fixed-shift softmax + MFMA PV ----------------
// Round-14 lesson: bulk per-lane ROW gathers from global (64 splits/instr) are
// VMEM-latency death; Pw belongs in LDS via coalesced staging. K gather is only
// 8 such instructions -> fine.
__global__ __launch_bounds__(256) void attn(
    const unsigned short* __restrict__ qh, const unsigned short* __restrict__ kh,
    const unsigned short* __restrict__ vT, const unsigned short* __restrict__ Pwh,
    unsigned short* __restrict__ yb) {
  __shared__ __fp16 PwS[96][72];
  __shared__ __fp16 pS[32][72];
  __shared__ float lS[32];

  const int t = threadIdx.x;
  const int lane = t & 63;
  const int wu = __builtin_amdgcn_readfirstlane(t >> 6);
  const int bh = blockIdx.x;
  const int b = bh >> 3;
  const int h = bh & 7;
  const int hkv = h >> 1;
  const int i0 = 480 - blockIdx.y * 32;  // heavy blocks first

  float l_lane[8];
#pragma unroll
  for (int r = 0; r < 8; ++r) l_lane[r] = 0.0f;
  float4v oacc[2] = {{0, 0, 0, 0}, {0, 0, 0, 0}};

  const int prow = (wu << 3) + 63 - lane;
  const int i_base = i0 + (wu << 3);
  const unsigned short* qbase = &qh[((b * Tt + i_base) * Hh + h) * Dd];

  // PV fragment roles
  const int i16 = (wu & 1) << 4;
  const int dt0 = (wu >> 1) << 1;
  const int lm = lane & 15;
  const int kq = (lane >> 4) << 3;
  const unsigned short* vTbase = &vT[((b * HKV + hkv) * 64) * 512];

  for (int jt0 = 0; jt0 <= i0 + 31; jt0 += 64) {
    __syncthreads();   // guards PwS restage + pS rewrite vs prior PV reads
    {
      int jr = t >> 2, dc = (t & 3) << 4;
      const int pb0 = h * 1023 + (i0 - jt0) + 448;
      const unsigned short* pwp = &Pwh[(pb0 + jr) * 64 + dc];
      *(uint4*)&PwS[jr][dc]     = *(const uint4*)&pwp[0];
      *(uint4*)&PwS[jr][dc + 8] = *(const uint4*)&pwp[8];
      int pr2 = 64 + (t >> 3), dc2 = (t & 7) << 3;
      if (pr2 < 95)
        *(uint4*)&PwS[pr2][dc2] = *(const uint4*)&Pwh[(pb0 + pr2) * 64 + dc2];
    }
    uint4 kr[8];
    {
      const uint4* kp = (const uint4*)&kh[((b * Tt + jt0 + lane) * HKV + hkv) * Dd];
#pragma unroll
      for (int c = 0; c < 8; ++c) kr[c] = kp[c];
    }
    __syncthreads();   // PwS ready

    // ---- score phase: lane = j; q broadcast from global, Pw from LDS, K regs ----
    const int j = jt0 + lane;
#pragma unroll
    for (int r = 0; r < 8; ++r) {
      const uint4* qp = (const uint4*)&qbase[r * (Hh * Dd)];  // wave-uniform
      float sr = 0.0f;
#pragma unroll
      for (int ch = 0; ch < 8; ++ch) {
        uint4 qu = qp[ch];
        uint4 pu = *(uint4*)&PwS[prow + r][ch << 3];
        sr = fdot2(u2h(qu.x) * u2h(pu.x), u2h(kr[ch].x), sr);
        sr = fdot2(u2h(qu.y) * u2h(pu.y), u2h(kr[ch].y), sr);
        sr = fdot2(u2h(qu.z) * u2h(pu.z), u2h(kr[ch].z), sr);
        sr = fdot2(u2h(qu.w) * u2h(pu.w), u2h(kr[ch].w), sr);
      }
      float sv = (j <= i_base + r) ? sr * 0.125f : -1e30f;
      float p = __expf(sv - 6.0f);   // fixed shift: exact softmax, no reduce
      l_lane[r] += p;
      pS[(wu << 3) + r][lane] = (__fp16)p;   // b16 store, 2-way banks
    }
    __syncthreads();   // pS ready for all waves

    // ---- PV phase: MFMA f16, A from pS, B from vT (global, L1/L2-hot) ----
    half8 a0 = *(half8*)&pS[i16 + lm][kq];
    half8 a1 = *(half8*)&pS[i16 + lm][kq + 32];
#pragma unroll
    for (int dd = 0; dd < 2; ++dd) {
      const unsigned short* vp = vTbase + (((dt0 + dd) << 4) + lm) * 512 + jt0 + kq;
      half8 b0 = *(const half8*)&vp[0];
      half8 b1 = *(const half8*)&vp[32];
      oacc[dd] = __builtin_amdgcn_mfma_f32_16x16x32_f16(a0, b0, oacc[dd], 0, 0, 0);
      oacc[dd] = __builtin_amdgcn_mfma_f32_16x16x32_f16(a1, b1, oacc[dd], 0, 0, 0);
    }
  }

  // final l reduction (once), shared via lS
#pragma unroll
  for (int r = 0; r < 8; ++r) {
    float lr = wave_reduce_sum(l_lane[r]);
    if (lane == r) lS[(wu << 3) + r] = lr;
  }
  __syncthreads();

  // epilogue: C layout — row = i16 + quad*4 + reg, col = d-tile*16 + lm
#pragma unroll
  for (int dd = 0; dd < 2; ++dd) {
    const int d = ((dt0 + dd) << 4) + lm;
#pragma unroll
    for (int r = 0; r < 4; ++r) {
      const int irow = i16 + ((lane >> 4) << 2) + r;
      const float val = oacc[dd][r] / lS[irow];
      __hip_bfloat16 hv = __float2bfloat16(val);
      yb[((b * Tt + i0 + irow) * Hh + h) * Dd + d] = *(unsigned short*)&hv;
    }
  }
}

extern "C" void kernel_launch(void* const* d_in, const int* in_sizes, int n_in,
                              void* d_out, int out_size, void* d_ws, size_t ws_size,
                              hipStream_t stream) {
  const float* x     = (const float*)d_in[0];
  const float* Wq    = (const float*)d_in[1];
  const float* Wk    = (const float*)d_in[2];
  const float* Wv    = (const float*)d_in[3];
  const float* Wproj = (const float*)d_in[4];
  const float* P     = (const float*)d_in[5];
  const float* sigma = (const float*)d_in[6];
  float* out = (float*)d_out;

  float* ws = (float*)d_ws;
  unsigned short* qh  = (unsigned short*)ws;                // 2,097,152 h = 1,048,576 f
  unsigned short* kh  = (unsigned short*)(ws + 1048576);    // 1,048,576 h = 524,288 f
  unsigned short* vT  = (unsigned short*)(ws + 1572864);    // 1,048,576 h = 524,288 f
  unsigned short* Pwh = (unsigned short*)(ws + 2097152);    // 523,776 h -> 262,144 f
  unsigned short* yb  = (unsigned short*)(ws + 2359296);    // 2,097,152 h = 1,048,576 f
  unsigned short* Wtq = (unsigned short*)(ws + 3407872);    // 524,288 h = 262,144 f
  unsigned short* Wtp = (unsigned short*)(ws + 3670016);    // 262,144 h = 131,072 f

  prep<<<dim3(2238), 256, 0, stream>>>(Wq, Wk, Wv, Wproj, P, sigma, Wtq, Wtp, Pwh);
  qkv_mfma<<<dim3(64, 16), 256, 0, stream>>>(x, Wtq, qh, kh, vT);
  attn<<<dim3(64, 16), 256, 0, stream>>>(qh, kh, vT, Pwh, yb);
  proj_mfma<<<dim3(64, 8), 256, 0, stream>>>(yb, Wtp, out);
}